// Round 1
// baseline (127.272 us; speedup 1.0000x reference)
//
#include <hip/hip_runtime.h>
#include <hip/hip_bf16.h>
#include <math.h>

typedef short short8 __attribute__((ext_vector_type(8)));
typedef float floatx4 __attribute__((ext_vector_type(4)));

#define NB 4096
#define DD 128
static constexpr float EPSF = 1e-8f;
static constexpr float TEMP = 11.313708498984760390f; // sqrt(128)

static __device__ __forceinline__ short f2bf(float f) {
    __hip_bfloat16 h = __float2bfloat16(f);
    union { __hip_bfloat16 h; short s; } u; u.h = h; return u.s;
}
static __device__ __forceinline__ float bf2f(short s) {
    union { __hip_bfloat16 h; short s; } u; u.s = s;
    return __bfloat162float(u.h);
}

// Pack 8 consecutive fp32 -> bf16x8 fragment
static __device__ __forceinline__ short8 load_cvt8(const float* __restrict__ p) {
    float4 a = *(const float4*)p;
    float4 b = *(const float4*)(p + 4);
    short8 o;
    o[0] = f2bf(a.x); o[1] = f2bf(a.y); o[2] = f2bf(a.z); o[3] = f2bf(a.w);
    o[4] = f2bf(b.x); o[5] = f2bf(b.y); o[6] = f2bf(b.z); o[7] = f2bf(b.w);
    return o;
}

// Fragment-major offset for qn/kn: matrix row g (0..4095), k index kidx (0..127)
// layout: [g>>4][kidx>>5][(kidx>>3)&3 * 16 + (g&15)][kidx&7]
// => a wave's MFMA fragment load (lane = quad*16+m, 8 bf16) is 64 consecutive
//    16 B chunks = one fully-coalesced 1 KB load.
static __device__ __forceinline__ int frag_off(int g, int kidx) {
    return ((((g >> 4) * 4 + (kidx >> 5)) * 4 + ((kidx >> 3) & 3)) * 16
            + (g & 15)) * 8 + (kidx & 7);
}

// ---------------- projection + metric-normalize (MFMA, bf16) ----------------
// 256 blocks: 32 rows x 128 cols each. 4 waves, each 32x32.
// Outputs qn/kn in fragment-major layout (see frag_off).
__global__ __launch_bounds__(256) void proj_kernel(
    const float* __restrict__ qp, const float* __restrict__ kp,
    const float* __restrict__ Wq, const float* __restrict__ bq,
    const float* __restrict__ Wk, const float* __restrict__ bk,
    __hip_bfloat16* __restrict__ qn, __hip_bfloat16* __restrict__ kn,
    float* __restrict__ rq, float* __restrict__ rk)
{
    int t = threadIdx.x;
    int b = blockIdx.x;                 // 0..255; 128 per matrix

    int which = b >> 7;
    int row0 = (b & 127) * 32;
    const float* x    = which ? kp : qp;
    const float* W    = which ? Wk : Wq;
    const float* bias = which ? bk : bq;
    short* outv = which ? (short*)kn : (short*)qn;
    float* outr = which ? rk : rq;

    int lane = t & 63, wid = t >> 6;
    int m = lane & 15, quad = lane >> 4;
    int colb = wid * 32;                // wave col origin (4 waves x 32 cols)

    floatx4 acc[2][2];
    #pragma unroll
    for (int i = 0; i < 2; ++i)
        #pragma unroll
        for (int j = 0; j < 2; ++j)
            acc[i][j] = (floatx4){0.f, 0.f, 0.f, 0.f};

    #pragma unroll
    for (int ks = 0; ks < 4; ++ks) {
        int koff = ks * 32 + quad * 8;
        short8 af[2], bfr[2];
        #pragma unroll
        for (int rt = 0; rt < 2; ++rt)
            af[rt] = load_cvt8(x + (row0 + rt*16 + m) * DD + koff);
        #pragma unroll
        for (int ct = 0; ct < 2; ++ct)
            bfr[ct] = load_cvt8(W + (colb + ct*16 + m) * DD + koff);
        #pragma unroll
        for (int rt = 0; rt < 2; ++rt)
            #pragma unroll
            for (int ct = 0; ct < 2; ++ct)
                acc[rt][ct] = __builtin_amdgcn_mfma_f32_16x16x32_bf16(
                    af[rt], bfr[ct], acc[rt][ct], 0, 0, 0);
    }

    __shared__ float buf[4][32];
    __shared__ float nfb[32];

    float bv[2];
    #pragma unroll
    for (int ct = 0; ct < 2; ++ct) bv[ct] = bias[colb + ct*16 + m];

    // add bias; per-row sum of squares (this wave's 32 cols), reduce over m
    #pragma unroll
    for (int rt = 0; rt < 2; ++rt) {
        #pragma unroll
        for (int r = 0; r < 4; ++r) {
            float p = 0.0f;
            #pragma unroll
            for (int ct = 0; ct < 2; ++ct) {
                float v = acc[rt][ct][r] + bv[ct];
                acc[rt][ct][r] = v;
                p = fmaf(v, v, p);
            }
            p += __shfl_xor(p, 1); p += __shfl_xor(p, 2);
            p += __shfl_xor(p, 4); p += __shfl_xor(p, 8);
            if (m == 0) buf[wid][rt*16 + quad*4 + r] = p;
        }
    }
    __syncthreads();
    if (t < 32) {
        float s = buf[0][t] + buf[1][t] + buf[2][t] + buf[3][t];
        float fro = sqrtf(s*s*(1.0f/16384.0f) + s*(1.0f/64.0f) + 128.0f);
        float qnorm = sqrtf((s*s*(1.0f/128.0f) + s) / (fro + EPSF));
        nfb[t] = 1.0f / (qnorm + EPSF);
    }
    __syncthreads();

    // scale, round to bf16, store (fragment-major); row-sum of rounded squares
    #pragma unroll
    for (int rt = 0; rt < 2; ++rt) {
        #pragma unroll
        for (int r = 0; r < 4; ++r) {
            int lrow = rt*16 + quad*4 + r;      // block-local 0..31
            int g = row0 + lrow;                // global matrix row
            float nf = nfb[lrow];
            float u = 0.0f;
            #pragma unroll
            for (int ct = 0; ct < 2; ++ct) {
                float v = acc[rt][ct][r] * nf;
                short sb = f2bf(v);
                outv[frag_off(g, colb + ct*16 + m)] = sb;
                float vf = bf2f(sb);
                u = fmaf(vf, vf, u);
            }
            u += __shfl_xor(u, 1); u += __shfl_xor(u, 2);
            u += __shfl_xor(u, 4); u += __shfl_xor(u, 8);
            if (m == 0) buf[wid][lrow] = u;
        }
    }
    __syncthreads();
    if (t < 32)
        outr[row0 + t] = buf[0][t] + buf[1][t] + buf[2][t] + buf[3][t];
}

// ---------------- scores: block owns 16 FULL rows ---------------------------
// 256 blocks x 1024 threads (16 waves = 4/SIMD). Wave w owns cols
// [w*256, w*256+256): 16 tiles of 16 cols, e kept in regs (64 fp32/lane).
// SWAPPED MFMA OPERANDS: mfma(bfr, af) -- A/B input fragment layouts are
// identical for 16x16x32, so loads are unchanged; the C/D layout flips to
// lane = (m,quad) owning q-row (r0+m) and 4 CONSECUTIVE k-cols
// (colblk*16 + quad*4 + r). Epilogue becomes float4 nontemporal stores
// (16 store instrs/lane instead of 64 scalar dwords), row-sum state shrinks
// from rs[4]+16 shuffles to 1 scalar + 2 shuffles, rk loads become float4.
__global__ __launch_bounds__(1024) void score_rows(
    const __hip_bfloat16* __restrict__ qn, const __hip_bfloat16* __restrict__ kn,
    const float* __restrict__ rq, const float* __restrict__ rk,
    float* __restrict__ P)
{
    int lane = threadIdx.x & 63;
    int wid  = threadIdx.x >> 6;        // 0..15
    int m    = lane & 15;
    int quad = lane >> 4;

    int rowblk = blockIdx.x;            // 16 rows per block
    int r0 = rowblk * 16;
    int cs = wid * 256;                 // wave's column strip

    const short* qs  = (const short*)qn;
    const short* kks = (const short*)kn;

    // A fragments: 16 rows x K=128 (coalesced 1 KB loads)
    short8 af[4];
    #pragma unroll
    for (int k4 = 0; k4 < 4; ++k4)
        af[k4] = *(const short8*)(qs + ((rowblk*4 + k4)*64 + lane)*8);

    float rqv = rq[r0 + m];             // this lane's q-row |qn|^2

    floatx4 acc[4][4];                  // e values: 16 rows x 256 cols / 64 lanes
    float rs = 0.f;                     // partial row sum for row r0+m

    #pragma unroll
    for (int it = 0; it < 4; ++it) {
        #pragma unroll
        for (int ct = 0; ct < 4; ++ct) {
            int colblk = (cs >> 4) + it*4 + ct;
            short8 bfr[4];
            #pragma unroll
            for (int k4 = 0; k4 < 4; ++k4)
                bfr[k4] = *(const short8*)(kks + ((colblk*4 + k4)*64 + lane)*8);
            floatx4 a = (floatx4){0.f, 0.f, 0.f, 0.f};
            #pragma unroll
            for (int k4 = 0; k4 < 4; ++k4)
                a = __builtin_amdgcn_mfma_f32_16x16x32_bf16(bfr[k4], af[k4], a, 0, 0, 0);
            // lane holds: q-row r0+m, k-cols colblk*16 + quad*4 + r
            floatx4 rkv = *(const floatx4*)(rk + colblk*16 + quad*4);
            #pragma unroll
            for (int r = 0; r < 4; ++r) {
                float d2 = fmaf(-2.0f, a[r], rqv + rkv[r]);
                float d  = d2 > 0.0f ? __builtin_amdgcn_sqrtf(d2) : 0.0f;
                float e  = __expf(TEMP * __builtin_amdgcn_rcpf(1.0f + d));
                a[r] = e;
                rs += e;
            }
            acc[it][ct] = a;
        }
    }

    // rs is partial over this lane's 64 cols; reduce across the 4 quads
    rs += __shfl_xor(rs, 16);
    rs += __shfl_xor(rs, 32);

    __shared__ float sums[16][16];
    __shared__ float inv[16];
    if (lane < 16) sums[wid][lane] = rs;   // quad==0 lanes: m = lane
    __syncthreads();
    if (threadIdx.x < 16) {
        float s = 0.f;
        #pragma unroll
        for (int w = 0; w < 16; ++w) s += sums[w][threadIdx.x];
        inv[threadIdx.x] = __builtin_amdgcn_rcpf(s + EPSF);
    }
    __syncthreads();

    float invv = inv[m];

    // float4 nontemporal stores: lane writes 4 consecutive cols of its row.
    // P is write-once, never re-read -> bypass L2 to keep kn/qn resident.
    #pragma unroll
    for (int it = 0; it < 4; ++it) {
        #pragma unroll
        for (int ct = 0; ct < 4; ++ct) {
            floatx4 o = acc[it][ct] * invv;
            floatx4* dst = (floatx4*)(P + (size_t)(r0 + m) * NB
                                        + cs + it*64 + ct*16 + quad*4);
            __builtin_nontemporal_store(o, dst);
        }
    }
}

extern "C" void kernel_launch(void* const* d_in, const int* in_sizes, int n_in,
                              void* d_out, int out_size, void* d_ws, size_t ws_size,
                              hipStream_t stream) {
    const float* qp = (const float*)d_in[0];
    const float* kp = (const float*)d_in[1];
    const float* Wq = (const float*)d_in[2];
    const float* bq = (const float*)d_in[3];
    const float* Wk = (const float*)d_in[4];
    const float* bk = (const float*)d_in[5];
    float* P = (float*)d_out;

    char* ws = (char*)d_ws;
    __hip_bfloat16* qn = (__hip_bfloat16*)ws;                         // 1 MB
    __hip_bfloat16* kn = (__hip_bfloat16*)(ws + (size_t)NB*DD*2);     // 1 MB
    float* rq = (float*)(ws + (size_t)NB*DD*4);                       // 16 KB
    float* rk = (float*)(ws + (size_t)NB*DD*4 + (size_t)NB*4);        // 16 KB

    hipLaunchKernelGGL(proj_kernel, dim3(256), dim3(256), 0, stream,
                       qp, kp, Wq, bq, Wk, bk, qn, kn, rq, rk);
    hipLaunchKernelGGL(score_rows, dim3(256), dim3(1024), 0, stream,
                       qn, kn, rq, rk, P);
}

// Round 2
// 120.832 us; speedup vs baseline: 1.0533x; 1.0533x over previous
//
#include <hip/hip_runtime.h>
#include <hip/hip_bf16.h>
#include <math.h>

typedef short short8 __attribute__((ext_vector_type(8)));
typedef float floatx4 __attribute__((ext_vector_type(4)));

#define NB 4096
#define DD 128
static constexpr float EPSF = 1e-8f;
static constexpr float TEMP = 11.313708498984760390f; // sqrt(128)

static __device__ __forceinline__ short f2bf(float f) {
    __hip_bfloat16 h = __float2bfloat16(f);
    union { __hip_bfloat16 h; short s; } u; u.h = h; return u.s;
}
static __device__ __forceinline__ float bf2f(short s) {
    union { __hip_bfloat16 h; short s; } u; u.s = s;
    return __bfloat162float(u.h);
}

// Pack 8 consecutive fp32 -> bf16x8 fragment
static __device__ __forceinline__ short8 load_cvt8(const float* __restrict__ p) {
    float4 a = *(const float4*)p;
    float4 b = *(const float4*)(p + 4);
    short8 o;
    o[0] = f2bf(a.x); o[1] = f2bf(a.y); o[2] = f2bf(a.z); o[3] = f2bf(a.w);
    o[4] = f2bf(b.x); o[5] = f2bf(b.y); o[6] = f2bf(b.z); o[7] = f2bf(b.w);
    return o;
}

// Fragment-major offset for qn/kn: matrix row g (0..4095), k index kidx (0..127)
// layout: [g>>4][kidx>>5][(kidx>>3)&3 * 16 + (g&15)][kidx&7]
// => a wave's MFMA fragment load (lane = quad*16+m, 8 bf16) is 64 consecutive
//    16 B chunks = one fully-coalesced 1 KB load.
static __device__ __forceinline__ int frag_off(int g, int kidx) {
    return ((((g >> 4) * 4 + (kidx >> 5)) * 4 + ((kidx >> 3) & 3)) * 16
            + (g & 15)) * 8 + (kidx & 7);
}

// ---------------- projection + metric-normalize (MFMA, bf16) ----------------
// 256 blocks: 32 rows x 128 cols each. 4 waves, each 32x32.
// Outputs qn/kn in fragment-major layout (see frag_off).
__global__ __launch_bounds__(256) void proj_kernel(
    const float* __restrict__ qp, const float* __restrict__ kp,
    const float* __restrict__ Wq, const float* __restrict__ bq,
    const float* __restrict__ Wk, const float* __restrict__ bk,
    __hip_bfloat16* __restrict__ qn, __hip_bfloat16* __restrict__ kn,
    float* __restrict__ rq, float* __restrict__ rk)
{
    int t = threadIdx.x;
    int b = blockIdx.x;                 // 0..255; 128 per matrix

    int which = b >> 7;
    int row0 = (b & 127) * 32;
    const float* x    = which ? kp : qp;
    const float* W    = which ? Wk : Wq;
    const float* bias = which ? bk : bq;
    short* outv = which ? (short*)kn : (short*)qn;
    float* outr = which ? rk : rq;

    int lane = t & 63, wid = t >> 6;
    int m = lane & 15, quad = lane >> 4;
    int colb = wid * 32;                // wave col origin (4 waves x 32 cols)

    floatx4 acc[2][2];
    #pragma unroll
    for (int i = 0; i < 2; ++i)
        #pragma unroll
        for (int j = 0; j < 2; ++j)
            acc[i][j] = (floatx4){0.f, 0.f, 0.f, 0.f};

    #pragma unroll
    for (int ks = 0; ks < 4; ++ks) {
        int koff = ks * 32 + quad * 8;
        short8 af[2], bfr[2];
        #pragma unroll
        for (int rt = 0; rt < 2; ++rt)
            af[rt] = load_cvt8(x + (row0 + rt*16 + m) * DD + koff);
        #pragma unroll
        for (int ct = 0; ct < 2; ++ct)
            bfr[ct] = load_cvt8(W + (colb + ct*16 + m) * DD + koff);
        #pragma unroll
        for (int rt = 0; rt < 2; ++rt)
            #pragma unroll
            for (int ct = 0; ct < 2; ++ct)
                acc[rt][ct] = __builtin_amdgcn_mfma_f32_16x16x32_bf16(
                    af[rt], bfr[ct], acc[rt][ct], 0, 0, 0);
    }

    __shared__ float buf[4][32];
    __shared__ float nfb[32];

    float bv[2];
    #pragma unroll
    for (int ct = 0; ct < 2; ++ct) bv[ct] = bias[colb + ct*16 + m];

    // add bias; per-row sum of squares (this wave's 32 cols), reduce over m
    #pragma unroll
    for (int rt = 0; rt < 2; ++rt) {
        #pragma unroll
        for (int r = 0; r < 4; ++r) {
            float p = 0.0f;
            #pragma unroll
            for (int ct = 0; ct < 2; ++ct) {
                float v = acc[rt][ct][r] + bv[ct];
                acc[rt][ct][r] = v;
                p = fmaf(v, v, p);
            }
            p += __shfl_xor(p, 1); p += __shfl_xor(p, 2);
            p += __shfl_xor(p, 4); p += __shfl_xor(p, 8);
            if (m == 0) buf[wid][rt*16 + quad*4 + r] = p;
        }
    }
    __syncthreads();
    if (t < 32) {
        float s = buf[0][t] + buf[1][t] + buf[2][t] + buf[3][t];
        float fro = sqrtf(s*s*(1.0f/16384.0f) + s*(1.0f/64.0f) + 128.0f);
        float qnorm = sqrtf((s*s*(1.0f/128.0f) + s) / (fro + EPSF));
        nfb[t] = 1.0f / (qnorm + EPSF);
    }
    __syncthreads();

    // scale, round to bf16, store (fragment-major); row-sum of rounded squares
    #pragma unroll
    for (int rt = 0; rt < 2; ++rt) {
        #pragma unroll
        for (int r = 0; r < 4; ++r) {
            int lrow = rt*16 + quad*4 + r;      // block-local 0..31
            int g = row0 + lrow;                // global matrix row
            float nf = nfb[lrow];
            float u = 0.0f;
            #pragma unroll
            for (int ct = 0; ct < 2; ++ct) {
                float v = acc[rt][ct][r] * nf;
                short sb = f2bf(v);
                outv[frag_off(g, colb + ct*16 + m)] = sb;
                float vf = bf2f(sb);
                u = fmaf(vf, vf, u);
            }
            u += __shfl_xor(u, 1); u += __shfl_xor(u, 2);
            u += __shfl_xor(u, 4); u += __shfl_xor(u, 8);
            if (m == 0) buf[wid][lrow] = u;
        }
    }
    __syncthreads();
    if (t < 32)
        outr[row0 + t] = buf[0][t] + buf[1][t] + buf[2][t] + buf[3][t];
}

// ---------------- scores: block owns 16 FULL rows ---------------------------
// 256 blocks x 1024 threads (16 waves, 1 block/CU). Wave w owns cols
// [w*256, w*256+256): 16 tiles of 16 cols, e kept in regs (64 fp32/lane).
// Swapped MFMA operands: mfma(bfr, af) -> lane (m,quad) owns q-row (r0+m)
// and 4 CONSECUTIVE k-cols, so the epilogue is float4 stores.
// __launch_bounds__(1024, 4): 16 waves / 4 SIMDs = 4 waves/EU = 1 block/CU
// -> 128-reg per-wave budget. acc(64)+af(16)+bfr(16)+temps fits WITHOUT
// spilling (round-1 build capped at 64 VGPRs and spilled acc to scratch:
// WRITE_SIZE 84 MB vs 67 ideal, MfmaUtil 3%, latency-bound).
__global__ __launch_bounds__(1024, 4) void score_rows(
    const __hip_bfloat16* __restrict__ qn, const __hip_bfloat16* __restrict__ kn,
    const float* __restrict__ rq, const float* __restrict__ rk,
    float* __restrict__ P)
{
    int lane = threadIdx.x & 63;
    int wid  = threadIdx.x >> 6;        // 0..15
    int m    = lane & 15;
    int quad = lane >> 4;

    int rowblk = blockIdx.x;            // 16 rows per block
    int r0 = rowblk * 16;
    int cs = wid * 256;                 // wave's column strip

    const short* qs  = (const short*)qn;
    const short* kks = (const short*)kn;

    // A fragments: 16 rows x K=128 (coalesced 1 KB loads)
    short8 af[4];
    #pragma unroll
    for (int k4 = 0; k4 < 4; ++k4)
        af[k4] = *(const short8*)(qs + ((rowblk*4 + k4)*64 + lane)*8);

    float rqv = rq[r0 + m];             // this lane's q-row |qn|^2

    floatx4 acc[4][4];                  // e values: 16 rows x 256 cols / 64 lanes
    float rs = 0.f;                     // partial row sum for row r0+m

    #pragma unroll
    for (int it = 0; it < 4; ++it) {
        #pragma unroll
        for (int ct = 0; ct < 4; ++ct) {
            int colblk = (cs >> 4) + it*4 + ct;
            short8 bfr[4];
            #pragma unroll
            for (int k4 = 0; k4 < 4; ++k4)
                bfr[k4] = *(const short8*)(kks + ((colblk*4 + k4)*64 + lane)*8);
            floatx4 a = (floatx4){0.f, 0.f, 0.f, 0.f};
            #pragma unroll
            for (int k4 = 0; k4 < 4; ++k4)
                a = __builtin_amdgcn_mfma_f32_16x16x32_bf16(bfr[k4], af[k4], a, 0, 0, 0);
            // lane holds: q-row r0+m, k-cols colblk*16 + quad*4 + r
            floatx4 rkv = *(const floatx4*)(rk + colblk*16 + quad*4);
            #pragma unroll
            for (int r = 0; r < 4; ++r) {
                float d2 = fmaf(-2.0f, a[r], rqv + rkv[r]);
                float d  = d2 > 0.0f ? __builtin_amdgcn_sqrtf(d2) : 0.0f;
                float e  = __expf(TEMP * __builtin_amdgcn_rcpf(1.0f + d));
                a[r] = e;
                rs += e;
            }
            acc[it][ct] = a;
        }
    }

    // rs is partial over this lane's 64 cols; reduce across the 4 quads
    rs += __shfl_xor(rs, 16);
    rs += __shfl_xor(rs, 32);

    __shared__ float sums[16][16];
    __shared__ float inv[16];
    if (lane < 16) sums[wid][lane] = rs;   // quad==0 lanes: m = lane
    __syncthreads();
    if (threadIdx.x < 16) {
        float s = 0.f;
        #pragma unroll
        for (int w = 0; w < 16; ++w) s += sums[w][threadIdx.x];
        inv[threadIdx.x] = __builtin_amdgcn_rcpf(s + EPSF);
    }
    __syncthreads();

    float invv = inv[m];

    // float4 stores: lane writes 4 consecutive cols of its row. Regular
    // (cached) stores so L2 write-combines the 64 B half-lines; consecutive
    // ct tiles complete each 128 B line.
    #pragma unroll
    for (int it = 0; it < 4; ++it) {
        #pragma unroll
        for (int ct = 0; ct < 4; ++ct) {
            floatx4 o = acc[it][ct] * invv;
            *(floatx4*)(P + (size_t)(r0 + m) * NB
                          + cs + it*64 + ct*16 + quad*4) = o;
        }
    }
}

extern "C" void kernel_launch(void* const* d_in, const int* in_sizes, int n_in,
                              void* d_out, int out_size, void* d_ws, size_t ws_size,
                              hipStream_t stream) {
    const float* qp = (const float*)d_in[0];
    const float* kp = (const float*)d_in[1];
    const float* Wq = (const float*)d_in[2];
    const float* bq = (const float*)d_in[3];
    const float* Wk = (const float*)d_in[4];
    const float* bk = (const float*)d_in[5];
    float* P = (float*)d_out;

    char* ws = (char*)d_ws;
    __hip_bfloat16* qn = (__hip_bfloat16*)ws;                         // 1 MB
    __hip_bfloat16* kn = (__hip_bfloat16*)(ws + (size_t)NB*DD*2);     // 1 MB
    float* rq = (float*)(ws + (size_t)NB*DD*4);                       // 16 KB
    float* rk = (float*)(ws + (size_t)NB*DD*4 + (size_t)NB*4);        // 16 KB

    hipLaunchKernelGGL(proj_kernel, dim3(256), dim3(256), 0, stream,
                       qp, kp, Wq, bq, Wk, bk, qn, kn, rq, rk);
    hipLaunchKernelGGL(score_rows, dim3(256), dim3(1024), 0, stream,
                       qn, kn, rq, rk, P);
}

// Round 4
// 119.349 us; speedup vs baseline: 1.0664x; 1.0124x over previous
//
#include <hip/hip_runtime.h>
#include <hip/hip_bf16.h>
#include <math.h>

typedef short short8 __attribute__((ext_vector_type(8)));
typedef float floatx4 __attribute__((ext_vector_type(4)));

#define NB 4096
#define DD 128
static constexpr float EPSF = 1e-8f;
static constexpr float TEMP = 11.313708498984760390f; // sqrt(128)

static __device__ __forceinline__ short f2bf(float f) {
    __hip_bfloat16 h = __float2bfloat16(f);
    union { __hip_bfloat16 h; short s; } u; u.h = h; return u.s;
}
static __device__ __forceinline__ float bf2f(short s) {
    union { __hip_bfloat16 h; short s; } u; u.s = s;
    return __bfloat162float(u.h);
}

// Pack 8 consecutive fp32 -> bf16x8 fragment
static __device__ __forceinline__ short8 load_cvt8(const float* __restrict__ p) {
    float4 a = *(const float4*)p;
    float4 b = *(const float4*)(p + 4);
    short8 o;
    o[0] = f2bf(a.x); o[1] = f2bf(a.y); o[2] = f2bf(a.z); o[3] = f2bf(a.w);
    o[4] = f2bf(b.x); o[5] = f2bf(b.y); o[6] = f2bf(b.z); o[7] = f2bf(b.w);
    return o;
}

// Fragment-major offset for qn/kn: matrix row g (0..4095), k index kidx (0..127)
// layout: [g>>4][kidx>>5][(kidx>>3)&3 * 16 + (g&15)][kidx&7]
// => a wave's MFMA fragment load (lane = quad*16+m, 8 bf16) is 64 consecutive
//    16 B chunks = one fully-coalesced 1 KB load.
static __device__ __forceinline__ int frag_off(int g, int kidx) {
    return ((((g >> 4) * 4 + (kidx >> 5)) * 4 + ((kidx >> 3) & 3)) * 16
            + (g & 15)) * 8 + (kidx & 7);
}

// ---------------- projection + metric-normalize (MFMA, bf16) ----------------
// 512 blocks x 512 threads: 16 rows x 128 cols each; 8 waves, wave = 16x16.
// 2 blocks/CU -> 4 waves/SIMD. (Old 256x256 shape was 1 wave/SIMD: every
// global load's latency fully exposed -> ~30+ us for ~1 us of work, per the
// R1 decomposition: 127.3 total - 45.5 score - ~45 fill = ~37 unaccounted.)
__global__ __launch_bounds__(512) void proj_kernel(
    const float* __restrict__ qp, const float* __restrict__ kp,
    const float* __restrict__ Wq, const float* __restrict__ bq,
    const float* __restrict__ Wk, const float* __restrict__ bk,
    __hip_bfloat16* __restrict__ qn, __hip_bfloat16* __restrict__ kn,
    float* __restrict__ rq, float* __restrict__ rk)
{
    int t = threadIdx.x;
    int b = blockIdx.x;                 // 0..511; 256 per matrix

    int which = b >> 8;
    int row0 = (b & 255) * 16;
    const float* x    = which ? kp : qp;
    const float* W    = which ? Wk : Wq;
    const float* bias = which ? bk : bq;
    short* outv = which ? (short*)kn : (short*)qn;
    float* outr = which ? rk : rq;

    int lane = t & 63, wid = t >> 6;    // 8 waves
    int m = lane & 15, quad = lane >> 4;
    int colb = wid * 16;                // wave col origin (8 waves x 16 cols)

    floatx4 acc = (floatx4){0.f, 0.f, 0.f, 0.f};

    #pragma unroll
    for (int ks = 0; ks < 4; ++ks) {
        int koff = ks * 32 + quad * 8;
        short8 af  = load_cvt8(x + (row0 + m) * DD + koff);
        short8 bfr = load_cvt8(W + (colb + m) * DD + koff);
        acc = __builtin_amdgcn_mfma_f32_16x16x32_bf16(af, bfr, acc, 0, 0, 0);
    }

    __shared__ float buf[8][16];
    __shared__ float nfb[16];

    float bv = bias[colb + m];

    // add bias; per-row sum of squares (this wave's 16 cols), reduce over m
    #pragma unroll
    for (int r = 0; r < 4; ++r) {
        float v = acc[r] + bv;
        acc[r] = v;
        float p = v * v;
        p += __shfl_xor(p, 1); p += __shfl_xor(p, 2);
        p += __shfl_xor(p, 4); p += __shfl_xor(p, 8);
        if (m == 0) buf[wid][quad*4 + r] = p;
    }
    __syncthreads();
    if (t < 16) {
        float s = 0.f;
        #pragma unroll
        for (int w = 0; w < 8; ++w) s += buf[w][t];
        float fro = sqrtf(s*s*(1.0f/16384.0f) + s*(1.0f/64.0f) + 128.0f);
        float qnorm = sqrtf((s*s*(1.0f/128.0f) + s) / (fro + EPSF));
        nfb[t] = 1.0f / (qnorm + EPSF);
    }
    __syncthreads();

    // scale, round to bf16, store (fragment-major); row-sum of rounded squares
    #pragma unroll
    for (int r = 0; r < 4; ++r) {
        int lrow = quad*4 + r;              // block-local 0..15
        int g = row0 + lrow;                // global matrix row
        float nf = nfb[lrow];
        float v = acc[r] * nf;
        short sb = f2bf(v);
        outv[frag_off(g, colb + m)] = sb;
        float vf = bf2f(sb);
        float u = vf * vf;
        u += __shfl_xor(u, 1); u += __shfl_xor(u, 2);
        u += __shfl_xor(u, 4); u += __shfl_xor(u, 8);
        if (m == 0) buf[wid][lrow] = u;
    }
    __syncthreads();
    if (t < 16) {
        float s = 0.f;
        #pragma unroll
        for (int w = 0; w < 8; ++w) s += buf[w][t];
        outr[row0 + t] = s;
    }
}

// ---------------- scores: block owns 16 FULL rows ---------------------------
// (Reverted exactly to the R2-passing version; R3's 128 KB dynamic-LDS stash
// crashed the launch -- dynamic LDS > 64 KB needs hipFuncSetAttribute.)
// 256 blocks x 1024 threads (16 waves, 1 block/CU). Wave w owns cols
// [w*256, w*256+256). Swapped MFMA operands: mfma(bfr, af) -> lane (m,quad)
// owns q-row (r0+m) and 4 consecutive k-cols, so the epilogue is float4
// stores. __launch_bounds__(1024, 4) -> 128-reg budget, no spill.
__global__ __launch_bounds__(1024, 4) void score_rows(
    const __hip_bfloat16* __restrict__ qn, const __hip_bfloat16* __restrict__ kn,
    const float* __restrict__ rq, const float* __restrict__ rk,
    float* __restrict__ P)
{
    int lane = threadIdx.x & 63;
    int wid  = threadIdx.x >> 6;        // 0..15
    int m    = lane & 15;
    int quad = lane >> 4;

    int rowblk = blockIdx.x;            // 16 rows per block
    int r0 = rowblk * 16;
    int cs = wid * 256;                 // wave's column strip

    const short* qs  = (const short*)qn;
    const short* kks = (const short*)kn;

    // A fragments: 16 rows x K=128 (coalesced 1 KB loads)
    short8 af[4];
    #pragma unroll
    for (int k4 = 0; k4 < 4; ++k4)
        af[k4] = *(const short8*)(qs + ((rowblk*4 + k4)*64 + lane)*8);

    float rqv = rq[r0 + m];             // this lane's q-row |qn|^2

    floatx4 acc[4][4];                  // e values: 16 rows x 256 cols / 64 lanes
    float rs = 0.f;                     // partial row sum for row r0+m

    #pragma unroll
    for (int it = 0; it < 4; ++it) {
        #pragma unroll
        for (int ct = 0; ct < 4; ++ct) {
            int colblk = (cs >> 4) + it*4 + ct;
            short8 bfr[4];
            #pragma unroll
            for (int k4 = 0; k4 < 4; ++k4)
                bfr[k4] = *(const short8*)(kks + ((colblk*4 + k4)*64 + lane)*8);
            floatx4 a = (floatx4){0.f, 0.f, 0.f, 0.f};
            #pragma unroll
            for (int k4 = 0; k4 < 4; ++k4)
                a = __builtin_amdgcn_mfma_f32_16x16x32_bf16(bfr[k4], af[k4], a, 0, 0, 0);
            // lane holds: q-row r0+m, k-cols colblk*16 + quad*4 + r
            floatx4 rkv = *(const floatx4*)(rk + colblk*16 + quad*4);
            #pragma unroll
            for (int r = 0; r < 4; ++r) {
                float d2 = fmaf(-2.0f, a[r], rqv + rkv[r]);
                float d  = d2 > 0.0f ? __builtin_amdgcn_sqrtf(d2) : 0.0f;
                float e  = __expf(TEMP * __builtin_amdgcn_rcpf(1.0f + d));
                a[r] = e;
                rs += e;
            }
            acc[it][ct] = a;
        }
    }

    // rs is partial over this lane's 64 cols; reduce across the 4 quads
    rs += __shfl_xor(rs, 16);
    rs += __shfl_xor(rs, 32);

    __shared__ float sums[16][16];
    __shared__ float inv[16];
    if (lane < 16) sums[wid][lane] = rs;   // quad==0 lanes: m = lane
    __syncthreads();
    if (threadIdx.x < 16) {
        float s = 0.f;
        #pragma unroll
        for (int w = 0; w < 16; ++w) s += sums[w][threadIdx.x];
        inv[threadIdx.x] = __builtin_amdgcn_rcpf(s + EPSF);
    }
    __syncthreads();

    float invv = inv[m];

    // float4 stores: lane writes 4 consecutive cols of its row.
    #pragma unroll
    for (int it = 0; it < 4; ++it) {
        #pragma unroll
        for (int ct = 0; ct < 4; ++ct) {
            floatx4 o = acc[it][ct] * invv;
            *(floatx4*)(P + (size_t)(r0 + m) * NB
                          + cs + it*64 + ct*16 + quad*4) = o;
        }
    }
}

extern "C" void kernel_launch(void* const* d_in, const int* in_sizes, int n_in,
                              void* d_out, int out_size, void* d_ws, size_t ws_size,
                              hipStream_t stream) {
    const float* qp = (const float*)d_in[0];
    const float* kp = (const float*)d_in[1];
    const float* Wq = (const float*)d_in[2];
    const float* bq = (const float*)d_in[3];
    const float* Wk = (const float*)d_in[4];
    const float* bk = (const float*)d_in[5];
    float* P = (float*)d_out;

    char* ws = (char*)d_ws;
    __hip_bfloat16* qn = (__hip_bfloat16*)ws;                         // 1 MB
    __hip_bfloat16* kn = (__hip_bfloat16*)(ws + (size_t)NB*DD*2);     // 1 MB
    float* rq = (float*)(ws + (size_t)NB*DD*4);                       // 16 KB
    float* rk = (float*)(ws + (size_t)NB*DD*4 + (size_t)NB*4);        // 16 KB

    hipLaunchKernelGGL(proj_kernel, dim3(512), dim3(512), 0, stream,
                       qp, kp, Wq, bq, Wk, bk, qn, kn, rq, rk);
    hipLaunchKernelGGL(score_rows, dim3(256), dim3(1024), 0, stream,
                       qn, kn, rq, rk, P);
}